// Round 19
// baseline (254.341 us; speedup 1.0000x reference)
//
#include <hip/hip_runtime.h>
#include <stdint.h>

#define NS 4096   // samples
#define DD 2048   // feature dim
#define MC 1000   // classes
#define MP 1024   // padded classes
#define NLAB 2048 // labeled rows
#define NU 2048   // unlabeled rows

typedef __attribute__((ext_vector_type(8))) short bf16x8;
typedef __attribute__((ext_vector_type(4))) float f32x4;

__device__ inline unsigned short f2bf(float f) {
  union { float f; uint32_t u; } v; v.f = f;
  uint32_t u = v.u;
  u = u + 0x7fffu + ((u >> 16) & 1u);
  return (unsigned short)(u >> 16);
}
__device__ inline float bf2f(unsigned short h) {
  union { uint32_t u; float f; } v; v.u = ((uint32_t)h) << 16;
  return v.f;
}

__device__ inline void gload_lds16(const void* g, void* l) {
  __builtin_amdgcn_global_load_lds(
      (const __attribute__((address_space(1))) void*)g,
      (__attribute__((address_space(3))) void*)l, 16, 0, 0);
}

// ---------------- center + norm ----------------
__device__ inline float block_sum(float v, float* sm, int tid) {
  #pragma unroll
  for (int o = 32; o > 0; o >>= 1) v += __shfl_down(v, o, 64);
  __syncthreads();
  if ((tid & 63) == 0) sm[tid >> 6] = v;
  __syncthreads();
  return sm[0] + sm[1] + sm[2] + sm[3];
}

__global__ void center_norm_k(const float* __restrict__ fc7,
                              unsigned short* __restrict__ Xc,
                              float* __restrict__ invn) {
  __shared__ float sm[4];
  const int row = blockIdx.x;
  const int tid = threadIdx.x;
  const float4* src = (const float4*)(fc7 + (size_t)row * DD);
  float4 a = src[tid * 2];
  float4 b = src[tid * 2 + 1];
  float s = a.x + a.y + a.z + a.w + b.x + b.y + b.z + b.w;
  s = block_sum(s, sm, tid);
  const float mean = s * (1.f / (float)DD);
  float v0 = a.x - mean, v1 = a.y - mean, v2 = a.z - mean, v3 = a.w - mean;
  float v4 = b.x - mean, v5 = b.y - mean, v6 = b.z - mean, v7 = b.w - mean;
  float ss = v0*v0 + v1*v1 + v2*v2 + v3*v3 + v4*v4 + v5*v5 + v6*v6 + v7*v7;
  ss = block_sum(ss, sm, tid);
  if (tid == 0) invn[row] = rsqrtf(ss);
  ushort4 o0 = make_ushort4(f2bf(v0), f2bf(v1), f2bf(v2), f2bf(v3));
  ushort4 o1 = make_ushort4(f2bf(v4), f2bf(v5), f2bf(v6), f2bf(v7));
  ushort4* dst = (ushort4*)(Xc + (size_t)row * DD);
  dst[tid * 2] = o0;
  dst[tid * 2 + 1] = o1;
}

// ---------------- W GEMM, symmetric: 64x128 triangular tiles ----------------
// Double-buffered LDS, counted vmcnt(6) (next stage stays in flight through
// compute), raw barriers. f32 everywhere; bf16 only for cols >= NLAB.
__global__ void gemm_w_sym(const unsigned short* __restrict__ A,
                           const float* __restrict__ invn,
                           float* __restrict__ outF,
                           unsigned short* __restrict__ outBF) {
  __shared__ __align__(16) unsigned short As[2][64 * 64];
  __shared__ __align__(16) unsigned short Bs[2][128 * 64];
  const int tid = threadIdx.x;
  const int wv = tid >> 6;
  const int ln = tid & 63;
  const int wr = wv >> 1, wc = wv & 1;

  int b = (blockIdx.x & 7) * 132 + (blockIdx.x >> 3);
  int r = 0;
  while (b >= 32 - (r >> 1)) { b -= 32 - (r >> 1); ++r; }
  const int c = (r >> 1) + b;
  const int rowBase = r * 64;
  const int colBase = c * 128;
  const bool mirror = (c > (r >> 1));
  const bool bfStraight = (colBase >= NLAB);
  const bool bfMirror = mirror && (rowBase >= NLAB);
  const int fr = ln & 15, kg = ln >> 4;

  f32x4 acc[2][4];
  f32x4 zz = {0.f, 0.f, 0.f, 0.f};
  #pragma unroll
  for (int i = 0; i < 2; ++i)
    #pragma unroll
    for (int j = 0; j < 4; ++j) acc[i][j] = zz;

  const int lrow = ln >> 3;
  const int lcol = ((ln & 7) ^ lrow) * 8;
  const unsigned short* Ap = A + (size_t)(rowBase + lrow) * DD + lcol;
  const unsigned short* Bp = A + (size_t)(colBase + lrow) * DD + lcol;

  // stage: 6 gload_lds per wave (2 A + 4 B)
  auto stage = [&](int step, int buf) {
    const int k0 = step * 64;
    #pragma unroll
    for (int u = 0; u < 2; ++u) {
      const int rr = wv * 16 + u * 8;
      gload_lds16(Ap + (size_t)rr * DD + k0, &As[buf][rr * 64]);
    }
    #pragma unroll
    for (int u = 0; u < 4; ++u) {
      const int rr = wv * 32 + u * 8;
      gload_lds16(Bp + (size_t)rr * DD + k0, &Bs[buf][rr * 64]);
    }
  };

  stage(0, 0);
  constexpr int NSTEP = DD / 64;   // 32
  for (int step = 0; step < NSTEP; ++step) {
    const int cur = step & 1;
    __builtin_amdgcn_s_barrier();              // WAR: all waves done reading buf[cur^1]
    if (step + 1 < NSTEP) {
      stage(step + 1, cur ^ 1);
      asm volatile("s_waitcnt vmcnt(6)" ::: "memory");  // wait stage(step) only
    } else {
      asm volatile("s_waitcnt vmcnt(0)" ::: "memory");
    }
    __builtin_amdgcn_s_barrier();              // RAW: all waves' buf[cur] loads done
    __builtin_amdgcn_sched_barrier(0);
    #pragma unroll
    for (int kk = 0; kk < 2; ++kk) {
      bf16x8 af[2], bfr[4];
      #pragma unroll
      for (int i = 0; i < 2; ++i) {
        const int rr = wr * 32 + i * 16 + fr;
        af[i] = *(const bf16x8*)&As[cur][rr * 64 + ((kk * 4 + kg) ^ (rr & 7)) * 8];
      }
      #pragma unroll
      for (int j = 0; j < 4; ++j) {
        const int rr = wc * 64 + j * 16 + fr;
        bfr[j] = *(const bf16x8*)&Bs[cur][rr * 64 + ((kk * 4 + kg) ^ (rr & 7)) * 8];
      }
      #pragma unroll
      for (int i = 0; i < 2; ++i)
        #pragma unroll
        for (int j = 0; j < 4; ++j)
          acc[i][j] = __builtin_amdgcn_mfma_f32_16x16x32_bf16(af[i], bfr[j], acc[i][j], 0, 0, 0);
    }
  }

  const int cr = (ln >> 4) * 4;
  const int cc = ln & 15;
  #pragma unroll
  for (int i = 0; i < 2; ++i) {
    const int rb = rowBase + wr * 32 + i * 16 + cr;
    #pragma unroll
    for (int j = 0; j < 4; ++j) {
      const int cb = colBase + wc * 64 + j * 16 + cc;
      const float ic = invn[cb];
      float v[4];
      #pragma unroll
      for (int u = 0; u < 4; ++u) {
        float x = acc[i][j][u] * invn[rb + u] * ic;
        v[u] = x > 0.f ? x : 0.f;
        const size_t o = (size_t)(rb + u) * NS + cb;
        outF[o] = v[u];
        if (bfStraight) outBF[o] = f2bf(v[u]);
      }
      if (mirror) {
        const size_t o = (size_t)cb * NS + rb;
        *(float4*)&outF[o] = make_float4(v[0], v[1], v[2], v[3]);
        if (bfMirror)
          *(ushort4*)&outBF[o] = make_ushort4(f2bf(v[0]), f2bf(v[1]), f2bf(v[2]), f2bf(v[3]));
      }
    }
  }
}

// ---------------- replicator GEMM: K-window [z*512, +512) within U, split-K=4 ----------------
// pT is [MP][NU] (U columns only). Partials stored bf16.
__global__ void gemm_rep(const unsigned short* __restrict__ pT,
                         const unsigned short* __restrict__ Wbf,
                         unsigned short* __restrict__ q0, unsigned short* __restrict__ q1,
                         unsigned short* __restrict__ q2, unsigned short* __restrict__ q3) {
  __shared__ __align__(16) unsigned short As[64 * 64];
  __shared__ __align__(16) unsigned short Bs[128 * 64];
  const int tid = threadIdx.x;
  const int wv = tid >> 6;
  const int ln = tid & 63;
  const int wr = wv >> 1, wc = wv & 1;
  const int rowBase = blockIdx.y * 64;     // m
  const int colBase = blockIdx.x * 128;    // i'
  const int kRel = blockIdx.z * 512;       // j' window base (U-relative)
  unsigned short* __restrict__ outF = (blockIdx.z == 0) ? q0 : (blockIdx.z == 1) ? q1
                                    : (blockIdx.z == 2) ? q2 : q3;
  const int fr = ln & 15, kg = ln >> 4;

  f32x4 acc[2][4];
  f32x4 zz = {0.f, 0.f, 0.f, 0.f};
  #pragma unroll
  for (int i = 0; i < 2; ++i)
    #pragma unroll
    for (int j = 0; j < 4; ++j) acc[i][j] = zz;

  const int lrow = ln >> 3;
  const int lcol = ((ln & 7) ^ lrow) * 8;
  const unsigned short* Ap = pT + (size_t)(rowBase + lrow) * NU + kRel + lcol;
  const unsigned short* Bp = Wbf + (size_t)(NLAB + colBase + lrow) * NS + NLAB + kRel + lcol;

  for (int k0 = 0; k0 < 512; k0 += 64) {
    if (k0) __syncthreads();
    #pragma unroll
    for (int u = 0; u < 2; ++u) {
      const int rr = wv * 16 + u * 8;
      gload_lds16(Ap + (size_t)rr * NU + k0, &As[rr * 64]);
    }
    #pragma unroll
    for (int u = 0; u < 4; ++u) {
      const int rr = wv * 32 + u * 8;
      gload_lds16(Bp + (size_t)rr * NS + k0, &Bs[rr * 64]);
    }
    __syncthreads();
    #pragma unroll
    for (int kk = 0; kk < 2; ++kk) {
      bf16x8 af[2], bfr[4];
      #pragma unroll
      for (int i = 0; i < 2; ++i) {
        const int rr = wr * 32 + i * 16 + fr;
        af[i] = *(const bf16x8*)&As[rr * 64 + ((kk * 4 + kg) ^ (rr & 7)) * 8];
      }
      #pragma unroll
      for (int j = 0; j < 4; ++j) {
        const int rr = wc * 64 + j * 16 + fr;
        bfr[j] = *(const bf16x8*)&Bs[rr * 64 + ((kk * 4 + kg) ^ (rr & 7)) * 8];
      }
      #pragma unroll
      for (int i = 0; i < 2; ++i)
        #pragma unroll
        for (int j = 0; j < 4; ++j)
          acc[i][j] = __builtin_amdgcn_mfma_f32_16x16x32_bf16(af[i], bfr[j], acc[i][j], 0, 0, 0);
    }
  }

  const int cr = (ln >> 4) * 4;
  const int cc = ln & 15;
  #pragma unroll
  for (int i = 0; i < 2; ++i) {
    const int rb = rowBase + wr * 32 + i * 16 + cr;
    #pragma unroll
    for (int j = 0; j < 4; ++j) {
      const int cb = colBase + wc * 64 + j * 16 + cc;
      #pragma unroll
      for (int u = 0; u < 4; ++u)
        outF[(size_t)(rb + u) * NU + cb] = f2bf(acc[i][j][u]);
    }
  }
}

// ---------------- WL[m][i'] = sum_{j in L, labs[j]=m} Wbf[j][2048+i']  (W symmetric) ----------------
__global__ void wl_gather_k(const int* __restrict__ labs,
                            const unsigned short* __restrict__ Wbf,
                            float* __restrict__ WL) {
  __shared__ unsigned long long masks[32];
  const int m = blockIdx.x;
  const int t = threadIdx.x;
  const int wv = t >> 6, ln = t & 63;
  #pragma unroll
  for (int u = 0; u < 8; ++u) {
    const int w2 = wv * 8 + u;
    unsigned long long msk = __ballot(labs[w2 * 64 + ln] == m);
    if (ln == 0) masks[w2] = msk;
  }
  __syncthreads();
  float acc[8] = {0.f, 0.f, 0.f, 0.f, 0.f, 0.f, 0.f, 0.f};
  for (int w2 = 0; w2 < 32; ++w2) {
    unsigned long long m64 = masks[w2];
    while (m64) {
      const int bit = __ffsll(m64) - 1;
      m64 &= (m64 - 1);
      const int j = w2 * 64 + bit;          // ascending j -> deterministic order
      bf16x8 w = *(const bf16x8*)&Wbf[(size_t)j * NS + NLAB + t * 8];
      #pragma unroll
      for (int k = 0; k < 8; ++k) acc[k] += bf2f((unsigned short)w[k]);
    }
  }
  float* dst = WL + (size_t)m * NU + t * 8;
  *(float4*)dst = make_float4(acc[0], acc[1], acc[2], acc[3]);
  *(float4*)(dst + 4) = make_float4(acc[4], acc[5], acc[6], acc[7]);
}

// ---------------- init pT (U columns only): transpose probs ----------------
__global__ void init_pT_k(const float* __restrict__ probs,
                          unsigned short* __restrict__ pT) {
  __shared__ float t[32][33];
  const int tx = threadIdx.x, ty = threadIdx.y;
  const int i0 = blockIdx.x * 32, m0 = blockIdx.y * 32;  // i' in [0,NU), m
  const int i = i0 + ty;           // U-relative sample index
  const int m = m0 + tx;
  t[ty][tx] = (m < MC) ? probs[(size_t)(NLAB + i) * MC + m] : 0.f;
  __syncthreads();
  pT[(size_t)(m0 + ty) * NU + i0 + tx] = f2bf(t[tx][ty]);
}

// ---------------- labeled rows of ps: exact one-hot ----------------
__global__ void onehot_k(const int* __restrict__ labs, float* __restrict__ ps) {
  const int i = blockIdx.x;
  const int m4 = threadIdx.x * 4;
  if (m4 >= MC) return;
  const int lab = labs[i];
  float4 v;
  v.x = (lab == m4)     ? 1.f : 0.f;
  v.y = (lab == m4 + 1) ? 1.f : 0.f;
  v.z = (lab == m4 + 2) ? 1.f : 0.f;
  v.w = (lab == m4 + 3) ? 1.f : 0.f;
  *(float4*)&ps[(size_t)i * MC + m4] = v;
}

// ---------------- colsum + fused p*q -> pq (f32), 16 m-chunks of 64 ----------------
__global__ void colsum_part_k(const unsigned short* __restrict__ q0,
                              const unsigned short* __restrict__ q1,
                              const unsigned short* __restrict__ q2,
                              const unsigned short* __restrict__ q3,
                              const float* __restrict__ WL,
                              const unsigned short* __restrict__ pT,
                              float* __restrict__ pq,
                              float* __restrict__ part) {
  const int i = blockIdx.x * 256 + threadIdx.x;   // i' in [0, NU)
  const int c = blockIdx.y;                       // 16 m-chunks of 64
  float s = 0.f;
  #pragma unroll 4
  for (int mm = 0; mm < 64; ++mm) {
    const int m = c * 64 + mm;
    const size_t o = (size_t)m * NU + i;
    const float q = bf2f(q0[o]) + bf2f(q1[o]) + bf2f(q2[o]) + bf2f(q3[o]) + WL[o];
    const float f = bf2f(pT[o]) * q;
    s += f;
    pq[o] = f;
  }
  part[c * NU + i] = s;
}

__global__ void colsum_fin_k(const float* __restrict__ part, float* __restrict__ rsum) {
  const int i = blockIdx.x * 256 + threadIdx.x;
  float s = 0.f;
  #pragma unroll
  for (int c = 0; c < 16; ++c) s += part[c * NU + i];
  rsum[i] = 1.0f / s;
}

// ---------------- normalize pq -> next pT (bf16), contiguous ----------------
__global__ void scale_k(const float* __restrict__ pq,
                        const float* __restrict__ rsum,
                        unsigned short* __restrict__ pT) {
  const int g = blockIdx.x * 256 + threadIdx.x;
  const int idx = g * 4;
  const int i = idx & (NU - 1);
  float4 p = *(const float4*)(pq + idx);
  float4 r = *(const float4*)(rsum + i);
  ushort4 o = make_ushort4(f2bf(p.x * r.x), f2bf(p.y * r.y),
                           f2bf(p.z * r.z), f2bf(p.w * r.w));
  *(ushort4*)(pT + idx) = o;
}

// ---------------- final: transpose pq*rsum -> ps rows U ----------------
__global__ void final_k(const float* __restrict__ pq,
                        const float* __restrict__ rsum,
                        float* __restrict__ ps) {
  __shared__ float t[32][33];
  const int tx = threadIdx.x, ty = threadIdx.y;
  const int i0 = blockIdx.x * 32, m0 = blockIdx.y * 32;
  t[ty][tx] = pq[(size_t)(m0 + ty) * NU + i0 + tx];
  __syncthreads();
  const int i = i0 + ty, m = m0 + tx;
  if (m < MC)
    ps[(size_t)(NLAB + i) * MC + m] = t[tx][ty] * rsum[i];
}

extern "C" void kernel_launch(void* const* d_in, const int* in_sizes, int n_in,
                              void* d_out, int out_size, void* d_ws, size_t ws_size,
                              hipStream_t stream) {
  const float* fc7   = (const float*)d_in[0];
  const float* probs = (const float*)d_in[1];
  const int*   labs  = (const int*)d_in[2];

  char* ws = (char*)d_ws;
  unsigned short* Xc   = (unsigned short*)(ws);                              // 16 MiB
  unsigned short* Wbf  = (unsigned short*)(ws + (16ull << 20));              // 32 MiB
  unsigned short* pT   = (unsigned short*)(ws + (48ull << 20));              // 4 MiB
  unsigned short* q0   = (unsigned short*)(ws + (56ull << 20));              // 4 MiB
  unsigned short* q1   = (unsigned short*)(ws + (60ull << 20));              // 4 MiB
  unsigned short* q2   = (unsigned short*)(ws + (64ull << 20));              // 4 MiB
  unsigned short* q3   = (unsigned short*)(ws + (68ull << 20));              // 4 MiB
  float*          WL   = (float*)(ws + (72ull << 20));                       // 8 MiB
  float*          pq   = (float*)(ws + (80ull << 20));                       // 8 MiB
  float*          invn = (float*)(ws + (88ull << 20));                       // 16 KiB
  float*          rsum = (float*)(ws + (88ull << 20) + (16ull << 10));       // 8 KiB
  float*          part = (float*)(ws + (89ull << 20));                       // 128 KiB

  float* out_ps = (float*)d_out;                  // [4096][1000]
  float* out_W  = out_ps + (size_t)NS * MC;       // [4096][4096]

  center_norm_k<<<NS, 256, 0, stream>>>(fc7, Xc, invn);

  // W = relu(corr(Xc)), symmetric: 1056 triangular 64x128 blocks, dbuf+vmcnt(6)
  gemm_w_sym<<<1056, 256, 0, stream>>>(Xc, invn, out_W, Wbf);

  init_pT_k<<<dim3(NU / 32, MP / 32), dim3(32, 32), 0, stream>>>(probs, pT);
  onehot_k<<<NLAB, 256, 0, stream>>>(labs, out_ps);

  // WL: ballot-based label-match gather (deterministic ascending-j order)
  wl_gather_k<<<MP, 256, 0, stream>>>(labs, Wbf, WL);

  for (int it = 0; it < 5; ++it) {
    gemm_rep<<<dim3(NU / 128, MP / 64, 4), 256, 0, stream>>>(pT, Wbf, q0, q1, q2, q3);
    colsum_part_k<<<dim3(NU / 256, 16), 256, 0, stream>>>(q0, q1, q2, q3, WL, pT, pq, part);
    colsum_fin_k<<<NU / 256, 256, 0, stream>>>(part, rsum);
    if (it < 4)
      scale_k<<<(MP * NU / 4) / 256, 256, 0, stream>>>(pq, rsum, pT);
    else
      final_k<<<dim3(NU / 32, MP / 32), dim3(32, 32), 0, stream>>>(pq, rsum, out_ps);
  }
}

// Round 20
// 245.523 us; speedup vs baseline: 1.0359x; 1.0359x over previous
//
#include <hip/hip_runtime.h>
#include <stdint.h>

#define NS 4096   // samples
#define DD 2048   // feature dim
#define MC 1000   // classes
#define MP 1024   // padded classes
#define NLAB 2048 // labeled rows
#define NU 2048   // unlabeled rows

typedef __attribute__((ext_vector_type(8))) short bf16x8;
typedef __attribute__((ext_vector_type(4))) float f32x4;

__device__ inline unsigned short f2bf(float f) {
  union { float f; uint32_t u; } v; v.f = f;
  uint32_t u = v.u;
  u = u + 0x7fffu + ((u >> 16) & 1u);
  return (unsigned short)(u >> 16);
}
__device__ inline float bf2f(unsigned short h) {
  union { uint32_t u; float f; } v; v.u = ((uint32_t)h) << 16;
  return v.f;
}

__device__ inline void gload_lds16(const void* g, void* l) {
  __builtin_amdgcn_global_load_lds(
      (const __attribute__((address_space(1))) void*)g,
      (__attribute__((address_space(3))) void*)l, 16, 0, 0);
}

// ---------------- center + norm ----------------
__device__ inline float block_sum(float v, float* sm, int tid) {
  #pragma unroll
  for (int o = 32; o > 0; o >>= 1) v += __shfl_down(v, o, 64);
  __syncthreads();
  if ((tid & 63) == 0) sm[tid >> 6] = v;
  __syncthreads();
  return sm[0] + sm[1] + sm[2] + sm[3];
}

__global__ void center_norm_k(const float* __restrict__ fc7,
                              unsigned short* __restrict__ Xc,
                              float* __restrict__ invn) {
  __shared__ float sm[4];
  const int row = blockIdx.x;
  const int tid = threadIdx.x;
  const float4* src = (const float4*)(fc7 + (size_t)row * DD);
  float4 a = src[tid * 2];
  float4 b = src[tid * 2 + 1];
  float s = a.x + a.y + a.z + a.w + b.x + b.y + b.z + b.w;
  s = block_sum(s, sm, tid);
  const float mean = s * (1.f / (float)DD);
  float v0 = a.x - mean, v1 = a.y - mean, v2 = a.z - mean, v3 = a.w - mean;
  float v4 = b.x - mean, v5 = b.y - mean, v6 = b.z - mean, v7 = b.w - mean;
  float ss = v0*v0 + v1*v1 + v2*v2 + v3*v3 + v4*v4 + v5*v5 + v6*v6 + v7*v7;
  ss = block_sum(ss, sm, tid);
  if (tid == 0) invn[row] = rsqrtf(ss);
  ushort4 o0 = make_ushort4(f2bf(v0), f2bf(v1), f2bf(v2), f2bf(v3));
  ushort4 o1 = make_ushort4(f2bf(v4), f2bf(v5), f2bf(v6), f2bf(v7));
  ushort4* dst = (ushort4*)(Xc + (size_t)row * DD);
  dst[tid * 2] = o0;
  dst[tid * 2 + 1] = o1;
}

// ---------------- W GEMM, symmetric: 64x128 triangular tiles ----------------
// Single-buffer (R18-validated). f32 everywhere; bf16 only for cols >= NLAB.
__global__ void gemm_w_sym(const unsigned short* __restrict__ A,
                           const float* __restrict__ invn,
                           float* __restrict__ outF,
                           unsigned short* __restrict__ outBF) {
  __shared__ __align__(16) unsigned short As[64 * 64];
  __shared__ __align__(16) unsigned short Bs[128 * 64];
  const int tid = threadIdx.x;
  const int wv = tid >> 6;
  const int ln = tid & 63;
  const int wr = wv >> 1, wc = wv & 1;

  int b = (blockIdx.x & 7) * 132 + (blockIdx.x >> 3);
  int r = 0;
  while (b >= 32 - (r >> 1)) { b -= 32 - (r >> 1); ++r; }
  const int c = (r >> 1) + b;
  const int rowBase = r * 64;
  const int colBase = c * 128;
  const bool mirror = (c > (r >> 1));
  const bool bfStraight = (colBase >= NLAB);
  const bool bfMirror = mirror && (rowBase >= NLAB);
  const int fr = ln & 15, kg = ln >> 4;

  f32x4 acc[2][4];
  f32x4 zz = {0.f, 0.f, 0.f, 0.f};
  #pragma unroll
  for (int i = 0; i < 2; ++i)
    #pragma unroll
    for (int j = 0; j < 4; ++j) acc[i][j] = zz;

  const int lrow = ln >> 3;
  const int lcol = ((ln & 7) ^ lrow) * 8;
  const unsigned short* Ap = A + (size_t)(rowBase + lrow) * DD + lcol;
  const unsigned short* Bp = A + (size_t)(colBase + lrow) * DD + lcol;

  for (int k0 = 0; k0 < DD; k0 += 64) {
    if (k0) __syncthreads();
    #pragma unroll
    for (int u = 0; u < 2; ++u) {
      const int rr = wv * 16 + u * 8;
      gload_lds16(Ap + (size_t)rr * DD + k0, &As[rr * 64]);
    }
    #pragma unroll
    for (int u = 0; u < 4; ++u) {
      const int rr = wv * 32 + u * 8;
      gload_lds16(Bp + (size_t)rr * DD + k0, &Bs[rr * 64]);
    }
    __syncthreads();
    #pragma unroll
    for (int kk = 0; kk < 2; ++kk) {
      bf16x8 af[2], bfr[4];
      #pragma unroll
      for (int i = 0; i < 2; ++i) {
        const int rr = wr * 32 + i * 16 + fr;
        af[i] = *(const bf16x8*)&As[rr * 64 + ((kk * 4 + kg) ^ (rr & 7)) * 8];
      }
      #pragma unroll
      for (int j = 0; j < 4; ++j) {
        const int rr = wc * 64 + j * 16 + fr;
        bfr[j] = *(const bf16x8*)&Bs[rr * 64 + ((kk * 4 + kg) ^ (rr & 7)) * 8];
      }
      #pragma unroll
      for (int i = 0; i < 2; ++i)
        #pragma unroll
        for (int j = 0; j < 4; ++j)
          acc[i][j] = __builtin_amdgcn_mfma_f32_16x16x32_bf16(af[i], bfr[j], acc[i][j], 0, 0, 0);
    }
  }

  const int cr = (ln >> 4) * 4;
  const int cc = ln & 15;
  #pragma unroll
  for (int i = 0; i < 2; ++i) {
    const int rb = rowBase + wr * 32 + i * 16 + cr;
    #pragma unroll
    for (int j = 0; j < 4; ++j) {
      const int cb = colBase + wc * 64 + j * 16 + cc;
      const float ic = invn[cb];
      float v[4];
      #pragma unroll
      for (int u = 0; u < 4; ++u) {
        float x = acc[i][j][u] * invn[rb + u] * ic;
        v[u] = x > 0.f ? x : 0.f;
        const size_t o = (size_t)(rb + u) * NS + cb;
        outF[o] = v[u];
        if (bfStraight) outBF[o] = f2bf(v[u]);
      }
      if (mirror) {
        const size_t o = (size_t)cb * NS + rb;
        *(float4*)&outF[o] = make_float4(v[0], v[1], v[2], v[3]);
        if (bfMirror)
          *(ushort4*)&outBF[o] = make_ushort4(f2bf(v[0]), f2bf(v[1]), f2bf(v[2]), f2bf(v[3]));
      }
    }
  }
}

// ---------------- replicator GEMM: K-window [z*512, +512) within U, split-K=4 ----------------
// pT is [MP][NU] (U columns only). Partials stored bf16.
__global__ void gemm_rep(const unsigned short* __restrict__ pT,
                         const unsigned short* __restrict__ Wbf,
                         unsigned short* __restrict__ q0, unsigned short* __restrict__ q1,
                         unsigned short* __restrict__ q2, unsigned short* __restrict__ q3) {
  __shared__ __align__(16) unsigned short As[64 * 64];
  __shared__ __align__(16) unsigned short Bs[128 * 64];
  const int tid = threadIdx.x;
  const int wv = tid >> 6;
  const int ln = tid & 63;
  const int wr = wv >> 1, wc = wv & 1;
  const int rowBase = blockIdx.y * 64;     // m
  const int colBase = blockIdx.x * 128;    // i'
  const int kRel = blockIdx.z * 512;       // j' window base (U-relative)
  unsigned short* __restrict__ outF = (blockIdx.z == 0) ? q0 : (blockIdx.z == 1) ? q1
                                    : (blockIdx.z == 2) ? q2 : q3;
  const int fr = ln & 15, kg = ln >> 4;

  f32x4 acc[2][4];
  f32x4 zz = {0.f, 0.f, 0.f, 0.f};
  #pragma unroll
  for (int i = 0; i < 2; ++i)
    #pragma unroll
    for (int j = 0; j < 4; ++j) acc[i][j] = zz;

  const int lrow = ln >> 3;
  const int lcol = ((ln & 7) ^ lrow) * 8;
  const unsigned short* Ap = pT + (size_t)(rowBase + lrow) * NU + kRel + lcol;
  const unsigned short* Bp = Wbf + (size_t)(NLAB + colBase + lrow) * NS + NLAB + kRel + lcol;

  for (int k0 = 0; k0 < 512; k0 += 64) {
    if (k0) __syncthreads();
    #pragma unroll
    for (int u = 0; u < 2; ++u) {
      const int rr = wv * 16 + u * 8;
      gload_lds16(Ap + (size_t)rr * NU + k0, &As[rr * 64]);
    }
    #pragma unroll
    for (int u = 0; u < 4; ++u) {
      const int rr = wv * 32 + u * 8;
      gload_lds16(Bp + (size_t)rr * NS + k0, &Bs[rr * 64]);
    }
    __syncthreads();
    #pragma unroll
    for (int kk = 0; kk < 2; ++kk) {
      bf16x8 af[2], bfr[4];
      #pragma unroll
      for (int i = 0; i < 2; ++i) {
        const int rr = wr * 32 + i * 16 + fr;
        af[i] = *(const bf16x8*)&As[rr * 64 + ((kk * 4 + kg) ^ (rr & 7)) * 8];
      }
      #pragma unroll
      for (int j = 0; j < 4; ++j) {
        const int rr = wc * 64 + j * 16 + fr;
        bfr[j] = *(const bf16x8*)&Bs[rr * 64 + ((kk * 4 + kg) ^ (rr & 7)) * 8];
      }
      #pragma unroll
      for (int i = 0; i < 2; ++i)
        #pragma unroll
        for (int j = 0; j < 4; ++j)
          acc[i][j] = __builtin_amdgcn_mfma_f32_16x16x32_bf16(af[i], bfr[j], acc[i][j], 0, 0, 0);
    }
  }

  const int cr = (ln >> 4) * 4;
  const int cc = ln & 15;
  #pragma unroll
  for (int i = 0; i < 2; ++i) {
    const int rb = rowBase + wr * 32 + i * 16 + cr;
    #pragma unroll
    for (int j = 0; j < 4; ++j) {
      const int cb = colBase + wc * 64 + j * 16 + cc;
      #pragma unroll
      for (int u = 0; u < 4; ++u)
        outF[(size_t)(rb + u) * NU + cb] = f2bf(acc[i][j][u]);
    }
  }
}

// ---------------- WL[m][i'] = sum_{j in L, labs[j]=m} Wbf[j][2048+i']  (W symmetric) ----------------
__global__ void wl_gather_k(const int* __restrict__ labs,
                            const unsigned short* __restrict__ Wbf,
                            float* __restrict__ WL) {
  __shared__ unsigned long long masks[32];
  const int m = blockIdx.x;
  const int t = threadIdx.x;
  const int wv = t >> 6, ln = t & 63;
  #pragma unroll
  for (int u = 0; u < 8; ++u) {
    const int w2 = wv * 8 + u;
    unsigned long long msk = __ballot(labs[w2 * 64 + ln] == m);
    if (ln == 0) masks[w2] = msk;
  }
  __syncthreads();
  float acc[8] = {0.f, 0.f, 0.f, 0.f, 0.f, 0.f, 0.f, 0.f};
  for (int w2 = 0; w2 < 32; ++w2) {
    unsigned long long m64 = masks[w2];
    while (m64) {
      const int bit = __ffsll(m64) - 1;
      m64 &= (m64 - 1);
      const int j = w2 * 64 + bit;          // ascending j -> deterministic order
      bf16x8 w = *(const bf16x8*)&Wbf[(size_t)j * NS + NLAB + t * 8];
      #pragma unroll
      for (int k = 0; k < 8; ++k) acc[k] += bf2f((unsigned short)w[k]);
    }
  }
  float* dst = WL + (size_t)m * NU + t * 8;
  *(float4*)dst = make_float4(acc[0], acc[1], acc[2], acc[3]);
  *(float4*)(dst + 4) = make_float4(acc[4], acc[5], acc[6], acc[7]);
}

// ---------------- init pT (U columns only): transpose probs ----------------
__global__ void init_pT_k(const float* __restrict__ probs,
                          unsigned short* __restrict__ pT) {
  __shared__ float t[32][33];
  const int tx = threadIdx.x, ty = threadIdx.y;
  const int i0 = blockIdx.x * 32, m0 = blockIdx.y * 32;  // i' in [0,NU), m
  const int i = i0 + ty;           // U-relative sample index
  const int m = m0 + tx;
  t[ty][tx] = (m < MC) ? probs[(size_t)(NLAB + i) * MC + m] : 0.f;
  __syncthreads();
  pT[(size_t)(m0 + ty) * NU + i0 + tx] = f2bf(t[tx][ty]);
}

// ---------------- labeled rows of ps: exact one-hot ----------------
__global__ void onehot_k(const int* __restrict__ labs, float* __restrict__ ps) {
  const int i = blockIdx.x;
  const int m4 = threadIdx.x * 4;
  if (m4 >= MC) return;
  const int lab = labs[i];
  float4 v;
  v.x = (lab == m4)     ? 1.f : 0.f;
  v.y = (lab == m4 + 1) ? 1.f : 0.f;
  v.z = (lab == m4 + 2) ? 1.f : 0.f;
  v.w = (lab == m4 + 3) ? 1.f : 0.f;
  *(float4*)&ps[(size_t)i * MC + m4] = v;
}

// ---------------- colsum + fused p*q -> pq (f32), 16 m-chunks of 64 ----------------
__global__ void colsum_part_k(const unsigned short* __restrict__ q0,
                              const unsigned short* __restrict__ q1,
                              const unsigned short* __restrict__ q2,
                              const unsigned short* __restrict__ q3,
                              const float* __restrict__ WL,
                              const unsigned short* __restrict__ pT,
                              float* __restrict__ pq,
                              float* __restrict__ part) {
  const int i = blockIdx.x * 256 + threadIdx.x;   // i' in [0, NU)
  const int c = blockIdx.y;                       // 16 m-chunks of 64
  float s = 0.f;
  #pragma unroll 4
  for (int mm = 0; mm < 64; ++mm) {
    const int m = c * 64 + mm;
    const size_t o = (size_t)m * NU + i;
    const float q = bf2f(q0[o]) + bf2f(q1[o]) + bf2f(q2[o]) + bf2f(q3[o]) + WL[o];
    const float f = bf2f(pT[o]) * q;
    s += f;
    pq[o] = f;
  }
  part[c * NU + i] = s;
}

__global__ void colsum_fin_k(const float* __restrict__ part, float* __restrict__ rsum) {
  const int i = blockIdx.x * 256 + threadIdx.x;
  float s = 0.f;
  #pragma unroll
  for (int c = 0; c < 16; ++c) s += part[c * NU + i];
  rsum[i] = 1.0f / s;
}

// ---------------- normalize pq -> next pT (bf16), contiguous ----------------
__global__ void scale_k(const float* __restrict__ pq,
                        const float* __restrict__ rsum,
                        unsigned short* __restrict__ pT) {
  const int g = blockIdx.x * 256 + threadIdx.x;
  const int idx = g * 4;
  const int i = idx & (NU - 1);
  float4 p = *(const float4*)(pq + idx);
  float4 r = *(const float4*)(rsum + i);
  ushort4 o = make_ushort4(f2bf(p.x * r.x), f2bf(p.y * r.y),
                           f2bf(p.z * r.z), f2bf(p.w * r.w));
  *(ushort4*)(pT + idx) = o;
}

// ---------------- final: transpose pq*rsum -> ps rows U ----------------
__global__ void final_k(const float* __restrict__ pq,
                        const float* __restrict__ rsum,
                        float* __restrict__ ps) {
  __shared__ float t[32][33];
  const int tx = threadIdx.x, ty = threadIdx.y;
  const int i0 = blockIdx.x * 32, m0 = blockIdx.y * 32;
  t[ty][tx] = pq[(size_t)(m0 + ty) * NU + i0 + tx];
  __syncthreads();
  const int i = i0 + ty, m = m0 + tx;
  if (m < MC)
    ps[(size_t)(NLAB + i) * MC + m] = t[tx][ty] * rsum[i];
}

extern "C" void kernel_launch(void* const* d_in, const int* in_sizes, int n_in,
                              void* d_out, int out_size, void* d_ws, size_t ws_size,
                              hipStream_t stream) {
  const float* fc7   = (const float*)d_in[0];
  const float* probs = (const float*)d_in[1];
  const int*   labs  = (const int*)d_in[2];

  char* ws = (char*)d_ws;
  unsigned short* Xc   = (unsigned short*)(ws);                              // 16 MiB
  unsigned short* Wbf  = (unsigned short*)(ws + (16ull << 20));              // 32 MiB
  unsigned short* pT   = (unsigned short*)(ws + (48ull << 20));              // 4 MiB
  unsigned short* q0   = (unsigned short*)(ws + (56ull << 20));              // 4 MiB
  unsigned short* q1   = (unsigned short*)(ws + (60ull << 20));              // 4 MiB
  unsigned short* q2   = (unsigned short*)(ws + (64ull << 20));              // 4 MiB
  unsigned short* q3   = (unsigned short*)(ws + (68ull << 20));              // 4 MiB
  float*          WL   = (float*)(ws + (72ull << 20));                       // 8 MiB
  float*          pq   = (float*)(ws + (80ull << 20));                       // 8 MiB
  float*          invn = (float*)(ws + (88ull << 20));                       // 16 KiB
  float*          rsum = (float*)(ws + (88ull << 20) + (16ull << 10));       // 8 KiB
  float*          part = (float*)(ws + (89ull << 20));                       // 128 KiB

  float* out_ps = (float*)d_out;                  // [4096][1000]
  float* out_W  = out_ps + (size_t)NS * MC;       // [4096][4096]

  center_norm_k<<<NS, 256, 0, stream>>>(fc7, Xc, invn);

  // W = relu(corr(Xc)), symmetric: 1056 triangular 64x128 blocks
  gemm_w_sym<<<1056, 256, 0, stream>>>(Xc, invn, out_W, Wbf);

  init_pT_k<<<dim3(NU / 32, MP / 32), dim3(32, 32), 0, stream>>>(probs, pT);
  onehot_k<<<NLAB, 256, 0, stream>>>(labs, out_ps);

  // WL: ballot-based label-match gather (deterministic ascending-j order)
  wl_gather_k<<<MP, 256, 0, stream>>>(labs, Wbf, WL);

  for (int it = 0; it < 5; ++it) {
    gemm_rep<<<dim3(NU / 128, MP / 64, 4), 256, 0, stream>>>(pT, Wbf, q0, q1, q2, q3);
    colsum_part_k<<<dim3(NU / 256, 16), 256, 0, stream>>>(q0, q1, q2, q3, WL, pT, pq, part);
    colsum_fin_k<<<NU / 256, 256, 0, stream>>>(part, rsum);
    if (it < 4)
      scale_k<<<(MP * NU / 4) / 256, 256, 0, stream>>>(pq, rsum, pT);
    else
      final_k<<<dim3(NU / 32, MP / 32), dim3(32, 32), 0, stream>>>(pq, rsum, out_ps);
  }
}

// Round 22
// 245.440 us; speedup vs baseline: 1.0363x; 1.0003x over previous
//
#include <hip/hip_runtime.h>
#include <stdint.h>

#define NS 4096   // samples
#define DD 2048   // feature dim
#define MC 1000   // classes
#define MP 1024   // padded classes
#define NLAB 2048 // labeled rows
#define NU 2048   // unlabeled rows

typedef __attribute__((ext_vector_type(8))) short bf16x8;
typedef __attribute__((ext_vector_type(4))) float f32x4;

__device__ inline unsigned short f2bf(float f) {
  union { float f; uint32_t u; } v; v.f = f;
  uint32_t u = v.u;
  u = u + 0x7fffu + ((u >> 16) & 1u);
  return (unsigned short)(u >> 16);
}
__device__ inline float bf2f(unsigned short h) {
  union { uint32_t u; float f; } v; v.u = ((uint32_t)h) << 16;
  return v.f;
}

__device__ inline void gload_lds16(const void* g, void* l) {
  __builtin_amdgcn_global_load_lds(
      (const __attribute__((address_space(1))) void*)g,
      (__attribute__((address_space(3))) void*)l, 16, 0, 0);
}

// ---------------- center + norm ----------------
__device__ inline float block_sum(float v, float* sm, int tid) {
  #pragma unroll
  for (int o = 32; o > 0; o >>= 1) v += __shfl_down(v, o, 64);
  __syncthreads();
  if ((tid & 63) == 0) sm[tid >> 6] = v;
  __syncthreads();
  return sm[0] + sm[1] + sm[2] + sm[3];
}

__global__ void center_norm_k(const float* __restrict__ fc7,
                              unsigned short* __restrict__ Xc,
                              float* __restrict__ invn) {
  __shared__ float sm[4];
  const int row = blockIdx.x;
  const int tid = threadIdx.x;
  const float4* src = (const float4*)(fc7 + (size_t)row * DD);
  float4 a = src[tid * 2];
  float4 b = src[tid * 2 + 1];
  float s = a.x + a.y + a.z + a.w + b.x + b.y + b.z + b.w;
  s = block_sum(s, sm, tid);
  const float mean = s * (1.f / (float)DD);
  float v0 = a.x - mean, v1 = a.y - mean, v2 = a.z - mean, v3 = a.w - mean;
  float v4 = b.x - mean, v5 = b.y - mean, v6 = b.z - mean, v7 = b.w - mean;
  float ss = v0*v0 + v1*v1 + v2*v2 + v3*v3 + v4*v4 + v5*v5 + v6*v6 + v7*v7;
  ss = block_sum(ss, sm, tid);
  if (tid == 0) invn[row] = rsqrtf(ss);
  ushort4 o0 = make_ushort4(f2bf(v0), f2bf(v1), f2bf(v2), f2bf(v3));
  ushort4 o1 = make_ushort4(f2bf(v4), f2bf(v5), f2bf(v6), f2bf(v7));
  ushort4* dst = (ushort4*)(Xc + (size_t)row * DD);
  dst[tid * 2] = o0;
  dst[tid * 2 + 1] = o1;
}

// ---------------- W GEMM, symmetric: 64x128 triangular tiles ----------------
// f32 (never re-read) written NONTEMPORAL to avoid evicting Xc from L2/L3;
// bf16 (re-read by rep/wl) written cached, only for cols >= NLAB.
__global__ void gemm_w_sym(const unsigned short* __restrict__ A,
                           const float* __restrict__ invn,
                           float* __restrict__ outF,
                           unsigned short* __restrict__ outBF) {
  __shared__ __align__(16) unsigned short As[64 * 64];
  __shared__ __align__(16) unsigned short Bs[128 * 64];
  const int tid = threadIdx.x;
  const int wv = tid >> 6;
  const int ln = tid & 63;
  const int wr = wv >> 1, wc = wv & 1;

  int b = (blockIdx.x & 7) * 132 + (blockIdx.x >> 3);
  int r = 0;
  while (b >= 32 - (r >> 1)) { b -= 32 - (r >> 1); ++r; }
  const int c = (r >> 1) + b;
  const int rowBase = r * 64;
  const int colBase = c * 128;
  const bool mirror = (c > (r >> 1));
  const bool bfStraight = (colBase >= NLAB);
  const bool bfMirror = mirror && (rowBase >= NLAB);
  const int fr = ln & 15, kg = ln >> 4;

  f32x4 acc[2][4];
  f32x4 zz = {0.f, 0.f, 0.f, 0.f};
  #pragma unroll
  for (int i = 0; i < 2; ++i)
    #pragma unroll
    for (int j = 0; j < 4; ++j) acc[i][j] = zz;

  const int lrow = ln >> 3;
  const int lcol = ((ln & 7) ^ lrow) * 8;
  const unsigned short* Ap = A + (size_t)(rowBase + lrow) * DD + lcol;
  const unsigned short* Bp = A + (size_t)(colBase + lrow) * DD + lcol;

  for (int k0 = 0; k0 < DD; k0 += 64) {
    if (k0) __syncthreads();
    #pragma unroll
    for (int u = 0; u < 2; ++u) {
      const int rr = wv * 16 + u * 8;
      gload_lds16(Ap + (size_t)rr * DD + k0, &As[rr * 64]);
    }
    #pragma unroll
    for (int u = 0; u < 4; ++u) {
      const int rr = wv * 32 + u * 8;
      gload_lds16(Bp + (size_t)rr * DD + k0, &Bs[rr * 64]);
    }
    __syncthreads();
    #pragma unroll
    for (int kk = 0; kk < 2; ++kk) {
      bf16x8 af[2], bfr[4];
      #pragma unroll
      for (int i = 0; i < 2; ++i) {
        const int rr = wr * 32 + i * 16 + fr;
        af[i] = *(const bf16x8*)&As[rr * 64 + ((kk * 4 + kg) ^ (rr & 7)) * 8];
      }
      #pragma unroll
      for (int j = 0; j < 4; ++j) {
        const int rr = wc * 64 + j * 16 + fr;
        bfr[j] = *(const bf16x8*)&Bs[rr * 64 + ((kk * 4 + kg) ^ (rr & 7)) * 8];
      }
      #pragma unroll
      for (int i = 0; i < 2; ++i)
        #pragma unroll
        for (int j = 0; j < 4; ++j)
          acc[i][j] = __builtin_amdgcn_mfma_f32_16x16x32_bf16(af[i], bfr[j], acc[i][j], 0, 0, 0);
    }
  }

  const int cr = (ln >> 4) * 4;
  const int cc = ln & 15;
  #pragma unroll
  for (int i = 0; i < 2; ++i) {
    const int rb = rowBase + wr * 32 + i * 16 + cr;
    #pragma unroll
    for (int j = 0; j < 4; ++j) {
      const int cb = colBase + wc * 64 + j * 16 + cc;
      const float ic = invn[cb];
      float v[4];
      #pragma unroll
      for (int u = 0; u < 4; ++u) {
        float x = acc[i][j][u] * invn[rb + u] * ic;
        v[u] = x > 0.f ? x : 0.f;
        const size_t o = (size_t)(rb + u) * NS + cb;
        __builtin_nontemporal_store(v[u], &outF[o]);
        if (bfStraight) outBF[o] = f2bf(v[u]);
      }
      if (mirror) {
        const size_t o = (size_t)cb * NS + rb;
        f32x4 vv = {v[0], v[1], v[2], v[3]};
        __builtin_nontemporal_store(vv, (f32x4*)&outF[o]);
        if (bfMirror)
          *(ushort4*)&outBF[o] = make_ushort4(f2bf(v[0]), f2bf(v[1]), f2bf(v[2]), f2bf(v[3]));
      }
    }
  }
}

// ---------------- replicator GEMM: K-window [z*512, +512) within U, split-K=4 ----------------
// pT is [MP][NU] (U columns only). Partials stored bf16.
__global__ void gemm_rep(const unsigned short* __restrict__ pT,
                         const unsigned short* __restrict__ Wbf,
                         unsigned short* __restrict__ q0, unsigned short* __restrict__ q1,
                         unsigned short* __restrict__ q2, unsigned short* __restrict__ q3) {
  __shared__ __align__(16) unsigned short As[64 * 64];
  __shared__ __align__(16) unsigned short Bs[128 * 64];
  const int tid = threadIdx.x;
  const int wv = tid >> 6;
  const int ln = tid & 63;
  const int wr = wv >> 1, wc = wv & 1;
  const int rowBase = blockIdx.y * 64;     // m
  const int colBase = blockIdx.x * 128;    // i'
  const int kRel = blockIdx.z * 512;       // j' window base (U-relative)
  unsigned short* __restrict__ outF = (blockIdx.z == 0) ? q0 : (blockIdx.z == 1) ? q1
                                    : (blockIdx.z == 2) ? q2 : q3;
  const int fr = ln & 15, kg = ln >> 4;

  f32x4 acc[2][4];
  f32x4 zz = {0.f, 0.f, 0.f, 0.f};
  #pragma unroll
  for (int i = 0; i < 2; ++i)
    #pragma unroll
    for (int j = 0; j < 4; ++j) acc[i][j] = zz;

  const int lrow = ln >> 3;
  const int lcol = ((ln & 7) ^ lrow) * 8;
  const unsigned short* Ap = pT + (size_t)(rowBase + lrow) * NU + kRel + lcol;
  const unsigned short* Bp = Wbf + (size_t)(NLAB + colBase + lrow) * NS + NLAB + kRel + lcol;

  for (int k0 = 0; k0 < 512; k0 += 64) {
    if (k0) __syncthreads();
    #pragma unroll
    for (int u = 0; u < 2; ++u) {
      const int rr = wv * 16 + u * 8;
      gload_lds16(Ap + (size_t)rr * NU + k0, &As[rr * 64]);
    }
    #pragma unroll
    for (int u = 0; u < 4; ++u) {
      const int rr = wv * 32 + u * 8;
      gload_lds16(Bp + (size_t)rr * NS + k0, &Bs[rr * 64]);
    }
    __syncthreads();
    #pragma unroll
    for (int kk = 0; kk < 2; ++kk) {
      bf16x8 af[2], bfr[4];
      #pragma unroll
      for (int i = 0; i < 2; ++i) {
        const int rr = wr * 32 + i * 16 + fr;
        af[i] = *(const bf16x8*)&As[rr * 64 + ((kk * 4 + kg) ^ (rr & 7)) * 8];
      }
      #pragma unroll
      for (int j = 0; j < 4; ++j) {
        const int rr = wc * 64 + j * 16 + fr;
        bfr[j] = *(const bf16x8*)&Bs[rr * 64 + ((kk * 4 + kg) ^ (rr & 7)) * 8];
      }
      #pragma unroll
      for (int i = 0; i < 2; ++i)
        #pragma unroll
        for (int j = 0; j < 4; ++j)
          acc[i][j] = __builtin_amdgcn_mfma_f32_16x16x32_bf16(af[i], bfr[j], acc[i][j], 0, 0, 0);
    }
  }

  const int cr = (ln >> 4) * 4;
  const int cc = ln & 15;
  #pragma unroll
  for (int i = 0; i < 2; ++i) {
    const int rb = rowBase + wr * 32 + i * 16 + cr;
    #pragma unroll
    for (int j = 0; j < 4; ++j) {
      const int cb = colBase + wc * 64 + j * 16 + cc;
      #pragma unroll
      for (int u = 0; u < 4; ++u)
        outF[(size_t)(rb + u) * NU + cb] = f2bf(acc[i][j][u]);
    }
  }
}

// ---------------- WL[m][i'] = sum_{j in L, labs[j]=m} Wbf[j][2048+i']  (W symmetric) ----------------
__global__ void wl_gather_k(const int* __restrict__ labs,
                            const unsigned short* __restrict__ Wbf,
                            float* __restrict__ WL) {
  __shared__ unsigned long long masks[32];
  const int m = blockIdx.x;
  const int t = threadIdx.x;
  const int wv = t >> 6, ln = t & 63;
  #pragma unroll
  for (int u = 0; u < 8; ++u) {
    const int w2 = wv * 8 + u;
    unsigned long long msk = __ballot(labs[w2 * 64 + ln] == m);
    if (ln == 0) masks[w2] = msk;
  }
  __syncthreads();
  float acc[8] = {0.f, 0.f, 0.f, 0.f, 0.f, 0.f, 0.f, 0.f};
  for (int w2 = 0; w2 < 32; ++w2) {
    unsigned long long m64 = masks[w2];
    while (m64) {
      const int bit = __ffsll(m64) - 1;
      m64 &= (m64 - 1);
      const int j = w2 * 64 + bit;          // ascending j -> deterministic order
      bf16x8 w = *(const bf16x8*)&Wbf[(size_t)j * NS + NLAB + t * 8];
      #pragma unroll
      for (int k = 0; k < 8; ++k) acc[k] += bf2f((unsigned short)w[k]);
    }
  }
  float* dst = WL + (size_t)m * NU + t * 8;
  *(float4*)dst = make_float4(acc[0], acc[1], acc[2], acc[3]);
  *(float4*)(dst + 4) = make_float4(acc[4], acc[5], acc[6], acc[7]);
}

// ---------------- init pT (U columns only): transpose probs ----------------
__global__ void init_pT_k(const float* __restrict__ probs,
                          unsigned short* __restrict__ pT) {
  __shared__ float t[32][33];
  const int tx = threadIdx.x, ty = threadIdx.y;
  const int i0 = blockIdx.x * 32, m0 = blockIdx.y * 32;  // i' in [0,NU), m
  const int i = i0 + ty;           // U-relative sample index
  const int m = m0 + tx;
  t[ty][tx] = (m < MC) ? probs[(size_t)(NLAB + i) * MC + m] : 0.f;
  __syncthreads();
  pT[(size_t)(m0 + ty) * NU + i0 + tx] = f2bf(t[tx][ty]);
}

// ---------------- labeled rows of ps: exact one-hot ----------------
__global__ void onehot_k(const int* __restrict__ labs, float* __restrict__ ps) {
  const int i = blockIdx.x;
  const int m4 = threadIdx.x * 4;
  if (m4 >= MC) return;
  const int lab = labs[i];
  float4 v;
  v.x = (lab == m4)     ? 1.f : 0.f;
  v.y = (lab == m4 + 1) ? 1.f : 0.f;
  v.z = (lab == m4 + 2) ? 1.f : 0.f;
  v.w = (lab == m4 + 3) ? 1.f : 0.f;
  *(float4*)&ps[(size_t)i * MC + m4] = v;
}

// ---------------- colsum + fused p*q -> pq (f32), 16 m-chunks of 64 ----------------
__global__ void colsum_part_k(const unsigned short* __restrict__ q0,
                              const unsigned short* __restrict__ q1,
                              const unsigned short* __restrict__ q2,
                              const unsigned short* __restrict__ q3,
                              const float* __restrict__ WL,
                              const unsigned short* __restrict__ pT,
                              float* __restrict__ pq,
                              float* __restrict__ part) {
  const int i = blockIdx.x * 256 + threadIdx.x;   // i' in [0, NU)
  const int c = blockIdx.y;                       // 16 m-chunks of 64
  float s = 0.f;
  #pragma unroll 4
  for (int mm = 0; mm < 64; ++mm) {
    const int m = c * 64 + mm;
    const size_t o = (size_t)m * NU + i;
    const float q = bf2f(q0[o]) + bf2f(q1[o]) + bf2f(q2[o]) + bf2f(q3[o]) + WL[o];
    const float f = bf2f(pT[o]) * q;
    s += f;
    pq[o] = f;
  }
  part[c * NU + i] = s;
}

__global__ void colsum_fin_k(const float* __restrict__ part, float* __restrict__ rsum) {
  const int i = blockIdx.x * 256 + threadIdx.x;
  float s = 0.f;
  #pragma unroll
  for (int c = 0; c < 16; ++c) s += part[c * NU + i];
  rsum[i] = 1.0f / s;
}

// ---------------- normalize pq -> next pT (bf16), contiguous ----------------
__global__ void scale_k(const float* __restrict__ pq,
                        const float* __restrict__ rsum,
                        unsigned short* __restrict__ pT) {
  const int g = blockIdx.x * 256 + threadIdx.x;
  const int idx = g * 4;
  const int i = idx & (NU - 1);
  float4 p = *(const float4*)(pq + idx);
  float4 r = *(const float4*)(rsum + i);
  ushort4 o = make_ushort4(f2bf(p.x * r.x), f2bf(p.y * r.y),
                           f2bf(p.z * r.z), f2bf(p.w * r.w));
  *(ushort4*)(pT + idx) = o;
}

// ---------------- final: transpose pq*rsum -> ps rows U ----------------
__global__ void final_k(const float* __restrict__ pq,
                        const float* __restrict__ rsum,
                        float* __restrict__ ps) {
  __shared__ float t[32][33];
  const int tx = threadIdx.x, ty = threadIdx.y;
  const int i0 = blockIdx.x * 32, m0 = blockIdx.y * 32;
  t[ty][tx] = pq[(size_t)(m0 + ty) * NU + i0 + tx];
  __syncthreads();
  const int i = i0 + ty, m = m0 + tx;
  if (m < MC)
    ps[(size_t)(NLAB + i) * MC + m] = t[tx][ty] * rsum[i];
}

extern "C" void kernel_launch(void* const* d_in, const int* in_sizes, int n_in,
                              void* d_out, int out_size, void* d_ws, size_t ws_size,
                              hipStream_t stream) {
  const float* fc7   = (const float*)d_in[0];
  const float* probs = (const float*)d_in[1];
  const int*   labs  = (const int*)d_in[2];

  char* ws = (char*)d_ws;
  unsigned short* Xc   = (unsigned short*)(ws);                              // 16 MiB
  unsigned short* Wbf  = (unsigned short*)(ws + (16ull << 20));              // 32 MiB
  unsigned short* pT   = (unsigned short*)(ws + (48ull << 20));              // 4 MiB
  unsigned short* q0   = (unsigned short*)(ws + (56ull << 20));              // 4 MiB
  unsigned short* q1   = (unsigned short*)(ws + (60ull << 20));              // 4 MiB
  unsigned short* q2   = (unsigned short*)(ws + (64ull << 20));              // 4 MiB
  unsigned short* q3   = (unsigned short*)(ws + (68ull << 20));              // 4 MiB
  float*          WL   = (float*)(ws + (72ull << 20));                       // 8 MiB
  float*          pq   = (float*)(ws + (80ull << 20));                       // 8 MiB
  float*          invn = (float*)(ws + (88ull << 20));                       // 16 KiB
  float*          rsum = (float*)(ws + (88ull << 20) + (16ull << 10));       // 8 KiB
  float*          part = (float*)(ws + (89ull << 20));                       // 128 KiB

  float* out_ps = (float*)d_out;                  // [4096][1000]
  float* out_W  = out_ps + (size_t)NS * MC;       // [4096][4096]

  center_norm_k<<<NS, 256, 0, stream>>>(fc7, Xc, invn);

  // W = relu(corr(Xc)), symmetric: 1056 triangular 64x128 blocks (nt f32 stores)
  gemm_w_sym<<<1056, 256, 0, stream>>>(Xc, invn, out_W, Wbf);

  init_pT_k<<<dim3(NU / 32, MP / 32), dim3(32, 32), 0, stream>>>(probs, pT);
  onehot_k<<<NLAB, 256, 0, stream>>>(labs, out_ps);

  // WL: ballot-based label-match gather (deterministic ascending-j order)
  wl_gather_k<<<MP, 256, 0, stream>>>(labs, Wbf, WL);

  for (int it = 0; it < 5; ++it) {
    gemm_rep<<<dim3(NU / 128, MP / 64, 4), 256, 0, stream>>>(pT, Wbf, q0, q1, q2, q3);
    colsum_part_k<<<dim3(NU / 256, 16), 256, 0, stream>>>(q0, q1, q2, q3, WL, pT, pq, part);
    colsum_fin_k<<<NU / 256, 256, 0, stream>>>(part, rsum);
    if (it < 4)
      scale_k<<<(MP * NU / 4) / 256, 256, 0, stream>>>(pq, rsum, pT);
    else
      final_k<<<dim3(NU / 32, MP / 32), dim3(32, 32), 0, stream>>>(pq, rsum, out_ps);
  }
}